// Round 3
// baseline (962.831 us; speedup 1.0000x reference)
//
#include <hip/hip_runtime.h>
#include <hip/hip_cooperative_groups.h>
#include <math.h>

namespace cg = cooperative_groups;

#define HDIM 2048   // hidden size H (== D_IN)
#define DOUT 1024
#define NLAYER 4

__device__ __forceinline__ float sigmoidf_(float x) {
    return 1.0f / (1.0f + expf(-x));
}

// ---------------- Fused cooperative kernel ----------------
// 1024 blocks x 256 threads, 4 blocks/CU guaranteed by launch_bounds(256,4)
// (VGPR<=128) + 8.3 KB LDS. Block b computes h-cells {2b,2b+1}; wave w = gate w.
__launch_bounds__(256, 4)
__global__ void lstm_fused_k(const float* __restrict__ x,
                             const float* __restrict__ h0,
                             const float* __restrict__ c0,
                             const float* __restrict__ Wih,
                             const float* __restrict__ Whh,
                             const float* __restrict__ bih,
                             const float* __restrict__ bhh,
                             const float* __restrict__ fcw,
                             const float* __restrict__ fcb,
                             float* __restrict__ out,
                             float* __restrict__ hbuf)  // [NLAYER*HDIM] ws
{
    cg::grid_group grid = cg::this_grid();

    __shared__ float4 sh_in[HDIM / 4];  // 8 KiB
    __shared__ float  sgates[8];
    __shared__ float  part[4];
    __shared__ int    nzflag;

    const int tid   = threadIdx.x;
    const int lane  = tid & 63;
    const int wave  = tid >> 6;          // gate index (i,f,g,o)
    const int blk   = blockIdx.x;
    const int cell0 = blk * 2;

    for (int l = 0; l < NLAYER; ++l) {
        const float* hin   = (l == 0) ? x : (hbuf + (size_t)(l - 1) * HDIM);
        const float* hprev = h0 + l * HDIM;
        const float* cprev = c0 + l * HDIM;
        const float* Wi = Wih + (size_t)l * 4 * HDIM * HDIM;
        const float* Wh = Whh + (size_t)l * 4 * HDIM * HDIM;
        const float* bi = bih + l * 4 * HDIM;
        const float* bh = bhh + l * 4 * HDIM;

        if (tid == 0) nzflag = 0;
        __syncthreads();

        int nz = 0;
#pragma unroll
        for (int i = 0; i < 2; ++i) {
            const int idx = tid + i * 256;
            sh_in[idx] = ((const float4*)hin)[idx];
            float4 p = ((const float4*)hprev)[idx];
            if (p.x != 0.0f || p.y != 0.0f || p.z != 0.0f || p.w != 0.0f) nz = 1;
        }
        if (nz) nzflag = 1;  // benign race: all writers store 1
        __syncthreads();
        const int any_prev = nzflag;

        const int row0 = wave * HDIM + cell0;
        const float4* r0 = (const float4*)(Wi + (size_t)row0 * HDIM);
        const float4* r1 = (const float4*)(Wi + (size_t)(row0 + 1) * HDIM);

        float acc0 = 0.0f, acc1 = 0.0f;
#pragma unroll
        for (int it = 0; it < HDIM / 256; ++it) {
            const int idx = it * 64 + lane;
            const float4 a0 = r0[idx];
            const float4 a1 = r1[idx];
            const float4 hv = sh_in[idx];
            acc0 = fmaf(a0.x, hv.x, fmaf(a0.y, hv.y, fmaf(a0.z, hv.z, fmaf(a0.w, hv.w, acc0))));
            acc1 = fmaf(a1.x, hv.x, fmaf(a1.y, hv.y, fmaf(a1.z, hv.z, fmaf(a1.w, hv.w, acc1))));
        }

        if (any_prev) {  // h_prev==0 here: skipped, halves HBM traffic
            const float4* q0 = (const float4*)(Wh + (size_t)row0 * HDIM);
            const float4* q1 = (const float4*)(Wh + (size_t)(row0 + 1) * HDIM);
            const float4* pv4 = (const float4*)hprev;  // L2-resident
#pragma unroll
            for (int it = 0; it < HDIM / 256; ++it) {
                const int idx = it * 64 + lane;
                const float4 a0 = q0[idx];
                const float4 a1 = q1[idx];
                const float4 pv = pv4[idx];
                acc0 = fmaf(a0.x, pv.x, fmaf(a0.y, pv.y, fmaf(a0.z, pv.z, fmaf(a0.w, pv.w, acc0))));
                acc1 = fmaf(a1.x, pv.x, fmaf(a1.y, pv.y, fmaf(a1.z, pv.z, fmaf(a1.w, pv.w, acc1))));
            }
        }

#pragma unroll
        for (int off = 32; off > 0; off >>= 1) {
            acc0 += __shfl_down(acc0, off, 64);
            acc1 += __shfl_down(acc1, off, 64);
        }
        if (lane == 0) {
            sgates[wave * 2 + 0] = acc0 + bi[row0] + bh[row0];
            sgates[wave * 2 + 1] = acc1 + bi[row0 + 1] + bh[row0 + 1];
        }
        __syncthreads();

        if (tid < 2) {
            const float iv = sgates[0 * 2 + tid];
            const float fv = sgates[1 * 2 + tid];
            const float gv = sgates[2 * 2 + tid];
            const float ov = sgates[3 * 2 + tid];
            const float cp = cprev[cell0 + tid];
            const float cv = sigmoidf_(fv) * cp + sigmoidf_(iv) * tanhf(gv);
            hbuf[(size_t)l * HDIM + cell0 + tid] = sigmoidf_(ov) * tanhf(cv);
        }

        __builtin_amdgcn_fence(__ATOMIC_RELEASE, "agent");
        grid.sync();
        __builtin_amdgcn_fence(__ATOMIC_ACQUIRE, "agent");
    }

    // FC epilogue: out[blk] = fcw[blk,:] @ h3 + fcb[blk]
    {
        const float* h3 = hbuf + (size_t)3 * HDIM;
#pragma unroll
        for (int i = 0; i < 2; ++i) {
            const int idx = tid + i * 256;
            sh_in[idx] = ((const float4*)h3)[idx];
        }
        __syncthreads();

        const float4* r = (const float4*)(fcw + (size_t)blk * HDIM);
        float acc = 0.0f;
#pragma unroll
        for (int i = 0; i < 2; ++i) {
            const int idx = tid + i * 256;
            const float4 a = r[idx];
            const float4 hv = sh_in[idx];
            acc = fmaf(a.x, hv.x, fmaf(a.y, hv.y, fmaf(a.z, hv.z, fmaf(a.w, hv.w, acc))));
        }
#pragma unroll
        for (int off = 32; off > 0; off >>= 1) acc += __shfl_down(acc, off, 64);
        if (lane == 0) part[wave] = acc;
        __syncthreads();
        if (tid == 0)
            out[blk] = part[0] + part[1] + part[2] + part[3] + fcb[blk];
    }
}

// ---------------- Fallback path (proven 58 us, R1) ----------------
__launch_bounds__(256)
__global__ void lstm_layer_k(const float* __restrict__ Wi,
                             const float* __restrict__ Wh,
                             const float* __restrict__ bi,
                             const float* __restrict__ bh,
                             const float* __restrict__ hin,
                             const float* __restrict__ hprev,
                             const float* __restrict__ cprev,
                             float* __restrict__ hout)
{
    __shared__ float4 sh_in[HDIM / 4];
    __shared__ float  sgates[8];
    __shared__ int    nzflag;

    const int tid = threadIdx.x;
    if (tid == 0) nzflag = 0;
    __syncthreads();

    int nz = 0;
#pragma unroll
    for (int i = 0; i < 2; ++i) {
        const int idx = tid + i * 256;
        sh_in[idx] = ((const float4*)hin)[idx];
        float4 p = ((const float4*)hprev)[idx];
        if (p.x != 0.0f || p.y != 0.0f || p.z != 0.0f || p.w != 0.0f) nz = 1;
    }
    if (nz) nzflag = 1;
    __syncthreads();
    const int any_prev = nzflag;

    const int lane = tid & 63;
    const int wave = tid >> 6;
    const int cell0 = blockIdx.x * 2;
    const int row0 = wave * HDIM + cell0;

    const float4* r0 = (const float4*)(Wi + (size_t)row0 * HDIM);
    const float4* r1 = (const float4*)(Wi + (size_t)(row0 + 1) * HDIM);

    float acc0 = 0.0f, acc1 = 0.0f;
#pragma unroll
    for (int it = 0; it < HDIM / 256; ++it) {
        const int idx = it * 64 + lane;
        const float4 a0 = r0[idx];
        const float4 a1 = r1[idx];
        const float4 hv = sh_in[idx];
        acc0 = fmaf(a0.x, hv.x, fmaf(a0.y, hv.y, fmaf(a0.z, hv.z, fmaf(a0.w, hv.w, acc0))));
        acc1 = fmaf(a1.x, hv.x, fmaf(a1.y, hv.y, fmaf(a1.z, hv.z, fmaf(a1.w, hv.w, acc1))));
    }

    if (any_prev) {
        const float4* q0 = (const float4*)(Wh + (size_t)row0 * HDIM);
        const float4* q1 = (const float4*)(Wh + (size_t)(row0 + 1) * HDIM);
        const float4* pv4 = (const float4*)hprev;
#pragma unroll
        for (int it = 0; it < HDIM / 256; ++it) {
            const int idx = it * 64 + lane;
            const float4 a0 = q0[idx];
            const float4 a1 = q1[idx];
            const float4 pv = pv4[idx];
            acc0 = fmaf(a0.x, pv.x, fmaf(a0.y, pv.y, fmaf(a0.z, pv.z, fmaf(a0.w, pv.w, acc0))));
            acc1 = fmaf(a1.x, pv.x, fmaf(a1.y, pv.y, fmaf(a1.z, pv.z, fmaf(a1.w, pv.w, acc1))));
        }
    }

#pragma unroll
    for (int off = 32; off > 0; off >>= 1) {
        acc0 += __shfl_down(acc0, off, 64);
        acc1 += __shfl_down(acc1, off, 64);
    }
    if (lane == 0) {
        sgates[wave * 2 + 0] = acc0 + bi[row0] + bh[row0];
        sgates[wave * 2 + 1] = acc1 + bi[row0 + 1] + bh[row0 + 1];
    }
    __syncthreads();

    if (tid < 2) {
        const float iv = sgates[0 * 2 + tid];
        const float fv = sgates[1 * 2 + tid];
        const float gv = sgates[2 * 2 + tid];
        const float ov = sgates[3 * 2 + tid];
        const float cp = cprev[cell0 + tid];
        const float cv = sigmoidf_(fv) * cp + sigmoidf_(iv) * tanhf(gv);
        hout[cell0 + tid] = sigmoidf_(ov) * tanhf(cv);
    }
}

__launch_bounds__(256)
__global__ void fc_k(const float* __restrict__ W, const float* __restrict__ b,
                     const float* __restrict__ h, float* __restrict__ out)
{
    __shared__ float4 sh[HDIM / 4];
    const int tid = threadIdx.x;
#pragma unroll
    for (int i = 0; i < 2; ++i)
        sh[tid + i * 256] = ((const float4*)h)[tid + i * 256];
    __syncthreads();

    const int lane = tid & 63;
    const int wave = tid >> 6;
    const int row = blockIdx.x * 4 + wave;

    const float4* r = (const float4*)(W + (size_t)row * HDIM);
    float acc = 0.0f;
#pragma unroll
    for (int it = 0; it < HDIM / 256; ++it) {
        const int idx = it * 64 + lane;
        const float4 a = r[idx];
        const float4 hv = sh[idx];
        acc = fmaf(a.x, hv.x, fmaf(a.y, hv.y, fmaf(a.z, hv.z, fmaf(a.w, hv.w, acc))));
    }
#pragma unroll
    for (int off = 32; off > 0; off >>= 1) acc += __shfl_down(acc, off, 64);
    if (lane == 0) out[row] = acc + b[row];
}

extern "C" void kernel_launch(void* const* d_in, const int* in_sizes, int n_in,
                              void* d_out, int out_size, void* d_ws, size_t ws_size,
                              hipStream_t stream) {
    const float* x   = (const float*)d_in[0];
    const float* h0  = (const float*)d_in[1];
    const float* c0  = (const float*)d_in[2];
    const float* Wih = (const float*)d_in[3];
    const float* Whh = (const float*)d_in[4];
    const float* bih = (const float*)d_in[5];
    const float* bhh = (const float*)d_in[6];
    const float* fcw = (const float*)d_in[7];
    const float* fcb = (const float*)d_in[8];
    float* out  = (float*)d_out;
    float* hbuf = (float*)d_ws;  // NLAYER*HDIM floats

    void* args[] = {(void*)&x, (void*)&h0, (void*)&c0, (void*)&Wih, (void*)&Whh,
                    (void*)&bih, (void*)&bhh, (void*)&fcw, (void*)&fcb,
                    (void*)&out, (void*)&hbuf};
    hipError_t e = hipLaunchCooperativeKernel((void*)lstm_fused_k,
                                              dim3(HDIM / 2), dim3(256),
                                              args, 0, stream);
    if (e != hipSuccess) {
        // Fallback: 5 sequential launches (identical math -> identical output).
        const size_t wstride = (size_t)4 * HDIM * HDIM;
        const int    bstride = 4 * HDIM;
        float* hb0 = hbuf;
        float* hb1 = hbuf + HDIM;
        const float* hin = x;
        float* houts[4] = {hb0, hb1, hb0, hb1};
        for (int l = 0; l < 4; ++l) {
            lstm_layer_k<<<HDIM / 2, 256, 0, stream>>>(
                Wih + (size_t)l * wstride, Whh + (size_t)l * wstride,
                bih + l * bstride, bhh + l * bstride,
                hin, h0 + l * HDIM, c0 + l * HDIM, houts[l]);
            hin = houts[l];
        }
        fc_k<<<DOUT / 4, 256, 0, stream>>>(fcw, fcb, hb1, out);
    }
}

// Round 4
// 93.775 us; speedup vs baseline: 10.2675x; 10.2675x over previous
//
#include <hip/hip_runtime.h>
#include <math.h>

#define HDIM 2048   // hidden size H (== D_IN)
#define DOUT 1024
#define NLAYER 4
#define NBLK 256    // fused kernel: 1 block per CU
#define TPB 1024    // 16 waves per block

__device__ __forceinline__ float sigmoidf_(float x) {
    return 1.0f / (1.0f + expf(-x));
}

// Zero the barrier region (384 u32: 256 flags + pad + rel). Capture-safe init.
__global__ void init_bar_k(unsigned* __restrict__ bar) {
    bar[threadIdx.x] = 0u;
}

// ---------------- Fused cooperative kernel ----------------
// 256 blocks x 1024 threads. Block b owns h-cells [8b, 8b+8).
// Wave w: gate = w&3, cell pair = w>>2 -> 2 rows of W per wave per layer.
// Grid barrier: per-block flag store + block-0 aggregation + single rel flag.
__launch_bounds__(TPB, 1)
__global__ void lstm_fused_k(const float* __restrict__ x,
                             const float* __restrict__ h0,
                             const float* __restrict__ c0,
                             const float* __restrict__ Wih,
                             const float* __restrict__ Whh,
                             const float* __restrict__ bih,
                             const float* __restrict__ bhh,
                             const float* __restrict__ fcw,
                             const float* __restrict__ fcb,
                             float* __restrict__ out,
                             float* __restrict__ hbuf,   // [NLAYER*HDIM]
                             unsigned* __restrict__ bar) // [384]
{
    unsigned* flags = bar;        // one word per block
    unsigned* rel   = bar + 320;  // own cache line

    __shared__ float4 sh_in[HDIM / 4];   // 8 KiB
    __shared__ float  sgates[4][8];
    __shared__ int    nzflag;

    const int tid   = threadIdx.x;
    const int lane  = tid & 63;
    const int wave  = tid >> 6;     // 0..15
    const int gate  = wave & 3;     // i,f,g,o
    const int cp    = wave >> 2;    // 0..3 cell pair
    const int blk   = blockIdx.x;
    const int cell0 = blk * 8;

    for (int l = 0; l < NLAYER; ++l) {
        const float* hin   = (l == 0) ? x : (hbuf + (size_t)(l - 1) * HDIM);
        const float* hprev = h0 + l * HDIM;
        const float* cprev = c0 + l * HDIM;
        const float* Wi = Wih + (size_t)l * 4 * HDIM * HDIM;
        const float* Wh = Whh + (size_t)l * 4 * HDIM * HDIM;
        const float* bi = bih + l * 4 * HDIM;
        const float* bh = bhh + l * 4 * HDIM;

        if (tid == 0) nzflag = 0;
        __syncthreads();
        if (tid < HDIM / 4) {
            sh_in[tid] = ((const float4*)hin)[tid];
            float4 p = ((const float4*)hprev)[tid];
            if (p.x != 0.0f || p.y != 0.0f || p.z != 0.0f || p.w != 0.0f)
                nzflag = 1;  // benign race
        }
        __syncthreads();
        const int any_prev = nzflag;

        const int c0i  = cell0 + 2 * cp;
        const int row0 = gate * HDIM + c0i;
        const float4* r0 = (const float4*)(Wi + (size_t)row0 * HDIM);
        const float4* r1 = (const float4*)(Wi + (size_t)(row0 + 1) * HDIM);

        float acc0 = 0.0f, acc1 = 0.0f;
#pragma unroll
        for (int it = 0; it < 8; ++it) {
            const int idx = it * 64 + lane;
            const float4 a0 = r0[idx];
            const float4 a1 = r1[idx];
            const float4 hv = sh_in[idx];
            acc0 = fmaf(a0.x, hv.x, fmaf(a0.y, hv.y, fmaf(a0.z, hv.z, fmaf(a0.w, hv.w, acc0))));
            acc1 = fmaf(a1.x, hv.x, fmaf(a1.y, hv.y, fmaf(a1.z, hv.z, fmaf(a1.w, hv.w, acc1))));
        }

        if (any_prev) {  // h_prev==0 for this problem: skipped (halves traffic)
            const float4* q0 = (const float4*)(Wh + (size_t)row0 * HDIM);
            const float4* q1 = (const float4*)(Wh + (size_t)(row0 + 1) * HDIM);
            const float4* pv4 = (const float4*)hprev;
#pragma unroll
            for (int it = 0; it < 8; ++it) {
                const int idx = it * 64 + lane;
                const float4 a0 = q0[idx];
                const float4 a1 = q1[idx];
                const float4 pv = pv4[idx];
                acc0 = fmaf(a0.x, pv.x, fmaf(a0.y, pv.y, fmaf(a0.z, pv.z, fmaf(a0.w, pv.w, acc0))));
                acc1 = fmaf(a1.x, pv.x, fmaf(a1.y, pv.y, fmaf(a1.z, pv.z, fmaf(a1.w, pv.w, acc1))));
            }
        }

#pragma unroll
        for (int off = 32; off > 0; off >>= 1) {
            acc0 += __shfl_down(acc0, off, 64);
            acc1 += __shfl_down(acc1, off, 64);
        }
        if (lane == 0) {
            sgates[gate][2 * cp + 0] = acc0 + bi[row0] + bh[row0];
            sgates[gate][2 * cp + 1] = acc1 + bi[row0 + 1] + bh[row0 + 1];
        }
        __syncthreads();

        if (tid < 8) {
            const float iv = sgates[0][tid];
            const float fv = sgates[1][tid];
            const float gv = sgates[2][tid];
            const float ov = sgates[3][tid];
            const float cpv = cprev[cell0 + tid];
            const float cv = sigmoidf_(fv) * cpv + sigmoidf_(iv) * tanhf(gv);
            hbuf[(size_t)l * HDIM + cell0 + tid] = sigmoidf_(ov) * tanhf(cv);
        }
        __syncthreads();  // hbuf writes done block-wide

        // ---- grid barrier, phase = l+1 ----
        const unsigned ph = (unsigned)(l + 1);
        if (tid == 0)
            __hip_atomic_store(&flags[blk], ph, __ATOMIC_RELEASE,
                               __HIP_MEMORY_SCOPE_AGENT);
        if (blk == 0) {
            if (tid < NBLK) {
                while (__hip_atomic_load(&flags[tid], __ATOMIC_RELAXED,
                                         __HIP_MEMORY_SCOPE_AGENT) != ph)
                    __builtin_amdgcn_s_sleep(2);
            }
            __builtin_amdgcn_fence(__ATOMIC_ACQUIRE, "agent");
            __syncthreads();
            if (tid == 0)
                __hip_atomic_store(rel, ph, __ATOMIC_RELEASE,
                                   __HIP_MEMORY_SCOPE_AGENT);
        } else {
            if (tid == 0) {
                while (__hip_atomic_load(rel, __ATOMIC_RELAXED,
                                         __HIP_MEMORY_SCOPE_AGENT) != ph)
                    __builtin_amdgcn_s_sleep(2);
                __builtin_amdgcn_fence(__ATOMIC_ACQUIRE, "agent");
            }
            __syncthreads();
        }
    }

    // FC epilogue: 4 rows per block via waves 0..3.
    {
        const float* h3 = hbuf + (size_t)3 * HDIM;
        if (tid < HDIM / 4) sh_in[tid] = ((const float4*)h3)[tid];
        __syncthreads();
        if (wave < 4) {
            const int row = blk * 4 + wave;
            const float4* r = (const float4*)(fcw + (size_t)row * HDIM);
            float acc = 0.0f;
#pragma unroll
            for (int it = 0; it < 8; ++it) {
                const int idx = it * 64 + lane;
                const float4 a = r[idx];
                const float4 hv = sh_in[idx];
                acc = fmaf(a.x, hv.x, fmaf(a.y, hv.y, fmaf(a.z, hv.z, fmaf(a.w, hv.w, acc))));
            }
#pragma unroll
            for (int off = 32; off > 0; off >>= 1) acc += __shfl_down(acc, off, 64);
            if (lane == 0) out[row] = acc + fcb[row];
        }
    }
}

// ---------------- Fallback path (proven 58 us) ----------------
__launch_bounds__(256)
__global__ void lstm_layer_k(const float* __restrict__ Wi,
                             const float* __restrict__ Wh,
                             const float* __restrict__ bi,
                             const float* __restrict__ bh,
                             const float* __restrict__ hin,
                             const float* __restrict__ hprev,
                             const float* __restrict__ cprev,
                             float* __restrict__ hout)
{
    __shared__ float4 sh_in[HDIM / 4];
    __shared__ float  sgates[8];
    __shared__ int    nzflag;

    const int tid = threadIdx.x;
    if (tid == 0) nzflag = 0;
    __syncthreads();

    int nz = 0;
#pragma unroll
    for (int i = 0; i < 2; ++i) {
        const int idx = tid + i * 256;
        sh_in[idx] = ((const float4*)hin)[idx];
        float4 p = ((const float4*)hprev)[idx];
        if (p.x != 0.0f || p.y != 0.0f || p.z != 0.0f || p.w != 0.0f) nz = 1;
    }
    if (nz) nzflag = 1;
    __syncthreads();
    const int any_prev = nzflag;

    const int lane = tid & 63;
    const int wave = tid >> 6;
    const int cell0 = blockIdx.x * 2;
    const int row0 = wave * HDIM + cell0;

    const float4* r0 = (const float4*)(Wi + (size_t)row0 * HDIM);
    const float4* r1 = (const float4*)(Wi + (size_t)(row0 + 1) * HDIM);

    float acc0 = 0.0f, acc1 = 0.0f;
#pragma unroll
    for (int it = 0; it < 8; ++it) {
        const int idx = it * 64 + lane;
        const float4 a0 = r0[idx];
        const float4 a1 = r1[idx];
        const float4 hv = sh_in[idx];
        acc0 = fmaf(a0.x, hv.x, fmaf(a0.y, hv.y, fmaf(a0.z, hv.z, fmaf(a0.w, hv.w, acc0))));
        acc1 = fmaf(a1.x, hv.x, fmaf(a1.y, hv.y, fmaf(a1.z, hv.z, fmaf(a1.w, hv.w, acc1))));
    }

    if (any_prev) {
        const float4* q0 = (const float4*)(Wh + (size_t)row0 * HDIM);
        const float4* q1 = (const float4*)(Wh + (size_t)(row0 + 1) * HDIM);
        const float4* pv4 = (const float4*)hprev;
#pragma unroll
        for (int it = 0; it < 8; ++it) {
            const int idx = it * 64 + lane;
            const float4 a0 = q0[idx];
            const float4 a1 = q1[idx];
            const float4 pv = pv4[idx];
            acc0 = fmaf(a0.x, pv.x, fmaf(a0.y, pv.y, fmaf(a0.z, pv.z, fmaf(a0.w, pv.w, acc0))));
            acc1 = fmaf(a1.x, pv.x, fmaf(a1.y, pv.y, fmaf(a1.z, pv.z, fmaf(a1.w, pv.w, acc1))));
        }
    }

#pragma unroll
    for (int off = 32; off > 0; off >>= 1) {
        acc0 += __shfl_down(acc0, off, 64);
        acc1 += __shfl_down(acc1, off, 64);
    }
    if (lane == 0) {
        sgates[wave * 2 + 0] = acc0 + bi[row0] + bh[row0];
        sgates[wave * 2 + 1] = acc1 + bi[row0 + 1] + bh[row0 + 1];
    }
    __syncthreads();

    if (tid < 2) {
        const float iv = sgates[0 * 2 + tid];
        const float fv = sgates[1 * 2 + tid];
        const float gv = sgates[2 * 2 + tid];
        const float ov = sgates[3 * 2 + tid];
        const float cp = cprev[cell0 + tid];
        const float cv = sigmoidf_(fv) * cp + sigmoidf_(iv) * tanhf(gv);
        hout[cell0 + tid] = sigmoidf_(ov) * tanhf(cv);
    }
}

__launch_bounds__(256)
__global__ void fc_k(const float* __restrict__ W, const float* __restrict__ b,
                     const float* __restrict__ h, float* __restrict__ out)
{
    __shared__ float4 sh[HDIM / 4];
    const int tid = threadIdx.x;
#pragma unroll
    for (int i = 0; i < 2; ++i)
        sh[tid + i * 256] = ((const float4*)h)[tid + i * 256];
    __syncthreads();

    const int lane = tid & 63;
    const int wave = tid >> 6;
    const int row = blockIdx.x * 4 + wave;

    const float4* r = (const float4*)(W + (size_t)row * HDIM);
    float acc = 0.0f;
#pragma unroll
    for (int it = 0; it < 8; ++it) {
        const int idx = it * 64 + lane;
        const float4 a = r[idx];
        const float4 hv = sh[idx];
        acc = fmaf(a.x, hv.x, fmaf(a.y, hv.y, fmaf(a.z, hv.z, fmaf(a.w, hv.w, acc))));
    }
#pragma unroll
    for (int off = 32; off > 0; off >>= 1) acc += __shfl_down(acc, off, 64);
    if (lane == 0) out[row] = acc + b[row];
}

extern "C" void kernel_launch(void* const* d_in, const int* in_sizes, int n_in,
                              void* d_out, int out_size, void* d_ws, size_t ws_size,
                              hipStream_t stream) {
    const float* x   = (const float*)d_in[0];
    const float* h0  = (const float*)d_in[1];
    const float* c0  = (const float*)d_in[2];
    const float* Wih = (const float*)d_in[3];
    const float* Whh = (const float*)d_in[4];
    const float* bih = (const float*)d_in[5];
    const float* bhh = (const float*)d_in[6];
    const float* fcw = (const float*)d_in[7];
    const float* fcb = (const float*)d_in[8];
    float* out  = (float*)d_out;

    float*    hbuf = (float*)d_ws;                       // 32 KiB
    unsigned* bar  = (unsigned*)((char*)d_ws + 32 * 1024);  // 384 u32

    // Zero barrier flags every call (ws is poisoned once, never re-poisoned).
    init_bar_k<<<1, 384, 0, stream>>>(bar);

    void* args[] = {(void*)&x, (void*)&h0, (void*)&c0, (void*)&Wih, (void*)&Whh,
                    (void*)&bih, (void*)&bhh, (void*)&fcw, (void*)&fcb,
                    (void*)&out, (void*)&hbuf, (void*)&bar};
    hipError_t e = hipLaunchCooperativeKernel((void*)lstm_fused_k,
                                              dim3(NBLK), dim3(TPB),
                                              args, 0, stream);
    if (e != hipSuccess) {
        // Fallback: 5 sequential launches (identical math -> identical output).
        const size_t wstride = (size_t)4 * HDIM * HDIM;
        const int    bstride = 4 * HDIM;
        float* hb0 = hbuf;
        float* hb1 = hbuf + HDIM;
        const float* hin = x;
        float* houts[4] = {hb0, hb1, hb0, hb1};
        for (int l = 0; l < 4; ++l) {
            lstm_layer_k<<<HDIM / 2, 256, 0, stream>>>(
                Wih + (size_t)l * wstride, Whh + (size_t)l * wstride,
                bih + l * bstride, bhh + l * bstride,
                hin, h0 + l * HDIM, c0 + l * HDIM, houts[l]);
            hin = houts[l];
        }
        fc_k<<<DOUT / 4, 256, 0, stream>>>(fcw, fcb, hb1, out);
    }
}